// Round 2
// baseline (196.146 us; speedup 1.0000x reference)
//
#include <hip/hip_runtime.h>

#define BIGF 1e9f
#define JSTR 104      // cost row stride in floats (jo in [0,101] valid)
#define TT 512
#define DD 256
#define NB 64
#define DROWS 1088    // diag rows per batch (1023 used + prefetch overrun pad)

// ---------- DPP wave shifts: lane i <- lane i-1 (shr) / lane i+1 (shl); invalid lanes get `oldv`
__device__ __forceinline__ float dpp_wave_shr1(float x, float oldv) {
  int r = __builtin_amdgcn_update_dpp(__builtin_bit_cast(int, oldv),
                                      __builtin_bit_cast(int, x),
                                      0x138, 0xF, 0xF, false);  // WAVE_SHR1
  return __builtin_bit_cast(float, r);
}
__device__ __forceinline__ float dpp_wave_shl1(float x, float oldv) {
  int r = __builtin_amdgcn_update_dpp(__builtin_bit_cast(int, oldv),
                                      __builtin_bit_cast(int, x),
                                      0x130, 0xF, 0xF, false);  // WAVE_SHL1
  return __builtin_bit_cast(float, r);
}

// ---------- Kernel A: inverse row norms for x1 and x2 ----------
__global__ __launch_bounds__(256) void norm_kernel(const float* __restrict__ x1,
                                                   const float* __restrict__ x2,
                                                   float* __restrict__ rinv1,
                                                   float* __restrict__ rinv2) {
  const int w = threadIdx.x >> 6;
  const int lane = threadIdx.x & 63;
  const int row = blockIdx.x * 4 + w;  // 0 .. 65535
  const float* src;
  float* dst;
  if (row < NB * TT) {
    src = x1 + (size_t)row * DD;
    dst = rinv1 + row;
  } else {
    src = x2 + (size_t)(row - NB * TT) * DD;
    dst = rinv2 + (row - NB * TT);
  }
  const float4 v = *(const float4*)(src + lane * 4);
  float s = v.x * v.x + v.y * v.y + v.z * v.z + v.w * v.w;
#pragma unroll
  for (int off = 32; off > 0; off >>= 1) s += __shfl_down(s, off, 64);
  if (lane == 0) *dst = 1.0f / fmaxf(sqrtf(s), 1e-8f);
}

// ---------- Kernel B: banded cost = 1 - dot * rinv1[i] * rinv2[j], stored [b][i][jo] ----------
__global__ __launch_bounds__(256) void cost_kernel(const float* __restrict__ x1,
                                                   const float* __restrict__ x2,
                                                   const float* __restrict__ rinv1,
                                                   const float* __restrict__ rinv2,
                                                   float* __restrict__ costX) {
  const int jt = blockIdx.x;  // 0..2
  const int it = blockIdx.y;  // 0..7
  const int b = blockIdx.z;   // 0..63
  const int i0 = it * 64;
  const int j0 = i0 - 50 + jt * 64;
  __shared__ __align__(16) float s1[32][68];  // K-major, stride 68
  __shared__ __align__(16) float s2[32][68];
  const int t = threadIdx.x;
  const int tx = t & 15;
  const int ty = t >> 4;
  const int lr = t >> 3;  // 0..31
  const int lf = t & 7;   // float4 slot in 32-wide K chunk
  const float* x1b = x1 + (size_t)b * (TT * DD);
  const float* x2b = x2 + (size_t)b * (TT * DD);
  float acc[4][4];
#pragma unroll
  for (int r = 0; r < 4; ++r)
#pragma unroll
    for (int c = 0; c < 4; ++c) acc[r][c] = 0.f;

  for (int kc = 0; kc < DD; kc += 32) {
    __syncthreads();
#pragma unroll
    for (int h = 0; h < 2; ++h) {
      const int r = lr + h * 32;
      const int gi = i0 + r;  // always in [0,512)
      const float4 v1 = *(const float4*)(x1b + (size_t)gi * DD + kc + lf * 4);
      int gj = j0 + r;
      gj = gj < 0 ? 0 : (gj > TT - 1 ? TT - 1 : gj);
      const float4 v2 = *(const float4*)(x2b + (size_t)gj * DD + kc + lf * 4);
      s1[lf * 4 + 0][r] = v1.x; s1[lf * 4 + 1][r] = v1.y;
      s1[lf * 4 + 2][r] = v1.z; s1[lf * 4 + 3][r] = v1.w;
      s2[lf * 4 + 0][r] = v2.x; s2[lf * 4 + 1][r] = v2.y;
      s2[lf * 4 + 2][r] = v2.z; s2[lf * 4 + 3][r] = v2.w;
    }
    __syncthreads();
#pragma unroll
    for (int kk = 0; kk < 32; ++kk) {
      const float4 a = *(const float4*)&s1[kk][ty * 4];
      const float4 bb = *(const float4*)&s2[kk][tx * 4];
      acc[0][0] += a.x * bb.x; acc[0][1] += a.x * bb.y; acc[0][2] += a.x * bb.z; acc[0][3] += a.x * bb.w;
      acc[1][0] += a.y * bb.x; acc[1][1] += a.y * bb.y; acc[1][2] += a.y * bb.z; acc[1][3] += a.y * bb.w;
      acc[2][0] += a.z * bb.x; acc[2][1] += a.z * bb.y; acc[2][2] += a.z * bb.z; acc[2][3] += a.z * bb.w;
      acc[3][0] += a.w * bb.x; acc[3][1] += a.w * bb.y; acc[3][2] += a.w * bb.z; acc[3][3] += a.w * bb.w;
    }
  }
  float r1v[4], r2v[4];
#pragma unroll
  for (int r = 0; r < 4; ++r) r1v[r] = rinv1[b * TT + i0 + ty * 4 + r];
#pragma unroll
  for (int c = 0; c < 4; ++c) {
    int j = j0 + tx * 4 + c;
    int jc = j < 0 ? 0 : (j > TT - 1 ? TT - 1 : j);
    r2v[c] = rinv2[b * TT + jc];
  }
  float* cb = costX + (size_t)b * (TT * JSTR);
#pragma unroll
  for (int r = 0; r < 4; ++r) {
#pragma unroll
    for (int c = 0; c < 4; ++c) {
      const int i = i0 + ty * 4 + r;
      const int j = j0 + tx * 4 + c;
      const int jo = j - i + 50;
      if (j >= 0 && j < TT && jo >= 0 && jo <= 100) {
        cb[(size_t)i * JSTR + jo] = 1.0f - acc[r][c] * r1v[r] * r2v[c];
      }
    }
  }
}

// ---------- Kernel R: reshape [b][i][jo] -> diagonal-major [b][d][lane] ----------
// Lane l of diagonal d holds band cell k = 2l+p (p = d&1), i = (d>>1)+l+p-25, j = d-i.
// Invalid cells (outside band or outside [0,512)^2) get BIG; DP needs no masking.
__global__ __launch_bounds__(256) void reshape_kernel(const float* __restrict__ costX,
                                                      float* __restrict__ diag) {
  const int wv = (blockIdx.x * 256 + threadIdx.x) >> 6;  // global wave id
  const int l = threadIdx.x & 63;
  const int b = wv >> 10;
  const int d = wv & 1023;  // 0..1023 (1023 is pad, written BIG)
  const int p = d & 1;
  const int i = (d >> 1) + l + p - 25;
  const int j = d - i;
  const int k = 2 * l + p;
  float v = BIGF;
  if (d <= 1022 && k <= 100 && i >= 0 && i < TT && j >= 0 && j < TT) {
    v = costX[((size_t)b * TT + i) * JSTR + (100 - k)];
  }
  diag[((size_t)b * DROWS + d) * 64 + l] = v;
}

// ---------- Kernel C: anti-diagonal DP, one wave per batch, coalesced diag reads ----------
// Recurrence on band offset k: new[k] = c + min(prev1[k-1], prev1[k+1], prev2[k])
//   p=1 (odd d): k-1 -> same lane, k+1 -> wave_shl1;  p=0: k-1 -> wave_shr1, k+1 -> same lane.
// Each step loads 64 contiguous floats (256 B); 32-deep register ring prefetch.
__global__ __launch_bounds__(64) void dtw_dp_kernel(const float* __restrict__ diag,
                                                    float* __restrict__ out) {
  const int b = blockIdx.x;
  const int l = threadIdx.x;
  const float* base = diag + (size_t)b * (DROWS * 64);
  const float* pO = base + 64 + l;   // d = 1
  const float* pE = base + 128 + l;  // d = 2
  float cr[32];
#pragma unroll
  for (int t = 0; t < 16; ++t) {
    cr[2 * t] = *pO; pO += 128;
    cr[2 * t + 1] = *pE; pE += 128;
  }
  float prev2 = BIGF;
  const float c00 = base[25];          // cost(0,0) lives at d=0, lane 25
  float prev1 = (l == 25) ? c00 : BIGF;
  float ans = BIGF;
  for (int it = 0; it < 32; ++it) {
#pragma unroll
    for (int u = 0; u < 16; ++u) {
      // odd diagonal
      const float c1 = cr[2 * u];
      cr[2 * u] = *pO; pO += 128;  // prefetch d+32 (stays within DROWS pad)
      const float sh = dpp_wave_shl1(prev1, BIGF);
      const float m3 = fminf(fminf(prev1, sh), prev2);
      prev2 = prev1;
      prev1 = c1 + m3;
      // even diagonal
      const float c2 = cr[2 * u + 1];
      cr[2 * u + 1] = *pE; pE += 128;
      const float sh2 = dpp_wave_shr1(prev1, BIGF);
      const float m32 = fminf(fminf(sh2, prev1), prev2);
      prev2 = prev1;
      prev1 = c2 + m32;
      if (u == 14 && it == 31) ans = prev1;  // d = 1022 -> cell (511,511) at lane 25
    }
  }
  if (l == 25) out[b] = ans;
}

extern "C" void kernel_launch(void* const* d_in, const int* in_sizes, int n_in,
                              void* d_out, int out_size, void* d_ws, size_t ws_size,
                              hipStream_t stream) {
  const float* x1 = (const float*)d_in[0];
  const float* x2 = (const float*)d_in[1];
  float* out = (float*)d_out;
  float* costX = (float*)d_ws;                       // 64*512*104 floats = 13.6 MB
  float* diag = costX + (size_t)NB * TT * JSTR;      // 64*1088*64 floats = 17.8 MB
  float* rinv1 = diag + (size_t)NB * DROWS * 64;     // 64*512 floats
  float* rinv2 = rinv1 + NB * TT;                    // 64*512 floats

  norm_kernel<<<16384, 256, 0, stream>>>(x1, x2, rinv1, rinv2);
  dim3 g(3, 8, NB);
  cost_kernel<<<g, 256, 0, stream>>>(x1, x2, rinv1, rinv2, costX);
  reshape_kernel<<<NB * 1024 / 4, 256, 0, stream>>>(costX, diag);
  dtw_dp_kernel<<<NB, 64, 0, stream>>>(diag, out);
}

// Round 3
// 179.442 us; speedup vs baseline: 1.0931x; 1.0931x over previous
//
#include <hip/hip_runtime.h>

#define BIGF 1e9f
#define JSTR 104      // cost row stride in floats (jo in [0,101] valid)
#define TT 512
#define DD 256
#define NB 64
#define DROWS 1088    // diag rows per batch (1023 used + prefetch overrun pad)
#define SAK 40        // LDS row stride in bf16 (32 data + 8 pad; 80 B = odd number of 16B chunks)

typedef float floatx16 __attribute__((ext_vector_type(16)));
typedef __bf16 bf16x8 __attribute__((ext_vector_type(8)));

// ---------- DPP wave shifts: lane i <- lane i-1 (shr) / lane i+1 (shl); invalid lanes get `oldv`
__device__ __forceinline__ float dpp_wave_shr1(float x, float oldv) {
  int r = __builtin_amdgcn_update_dpp(__builtin_bit_cast(int, oldv),
                                      __builtin_bit_cast(int, x),
                                      0x138, 0xF, 0xF, false);  // WAVE_SHR1
  return __builtin_bit_cast(float, r);
}
__device__ __forceinline__ float dpp_wave_shl1(float x, float oldv) {
  int r = __builtin_amdgcn_update_dpp(__builtin_bit_cast(int, oldv),
                                      __builtin_bit_cast(int, x),
                                      0x130, 0xF, 0xF, false);  // WAVE_SHL1
  return __builtin_bit_cast(float, r);
}

// ---------- Kernel A: inverse row norms for x1 and x2 ----------
__global__ __launch_bounds__(256) void norm_kernel(const float* __restrict__ x1,
                                                   const float* __restrict__ x2,
                                                   float* __restrict__ rinv1,
                                                   float* __restrict__ rinv2) {
  const int w = threadIdx.x >> 6;
  const int lane = threadIdx.x & 63;
  const int row = blockIdx.x * 4 + w;  // 0 .. 65535
  const float* src;
  float* dst;
  if (row < NB * TT) {
    src = x1 + (size_t)row * DD;
    dst = rinv1 + row;
  } else {
    src = x2 + (size_t)(row - NB * TT) * DD;
    dst = rinv2 + (row - NB * TT);
  }
  const float4 v = *(const float4*)(src + lane * 4);
  float s = v.x * v.x + v.y * v.y + v.z * v.z + v.w * v.w;
#pragma unroll
  for (int off = 32; off > 0; off >>= 1) s += __shfl_down(s, off, 64);
  if (lane == 0) *dst = 1.0f / fmaxf(sqrtf(s), 1e-8f);
}

// ---------- Kernel B: banded cost via bf16 MFMA, stored [b][i][jo] ----------
// 64x64 (i,j) tile per block; 4 waves in 2x2; each wave one 32x32 MFMA accumulator.
__global__ __launch_bounds__(256) void cost_kernel(const float* __restrict__ x1,
                                                   const float* __restrict__ x2,
                                                   const float* __restrict__ rinv1,
                                                   const float* __restrict__ rinv2,
                                                   float* __restrict__ costX) {
  const int jt = blockIdx.x;  // 0..2
  const int it = blockIdx.y;  // 0..7
  const int b = blockIdx.z;   // 0..63
  const int i0 = it * 64;
  const int j0 = i0 - 50 + jt * 64;

  __shared__ __align__(16) __bf16 sA[64 * SAK];
  __shared__ __align__(16) __bf16 sB[64 * SAK];

  const int t = threadIdx.x;
  const int lane = t & 63;
  const int w = t >> 6;       // wave 0..3
  const int wi = w >> 1;      // i-subtile (0/1)
  const int wj = w & 1;       // j-subtile (0/1)
  const int ln = lane & 31;
  const int kh = lane >> 5;   // k-half (0/1)

  // staging mapping: thread t loads row (t>>2), 8 floats at quarter (t&3)
  const int sr = t >> 2;
  const int sq = t & 3;
  const float* x1b = x1 + (size_t)b * (TT * DD);
  const float* x2b = x2 + (size_t)b * (TT * DD);
  int gj = j0 + sr;
  gj = gj < 0 ? 0 : (gj > TT - 1 ? TT - 1 : gj);
  const float* pAg = x1b + (size_t)(i0 + sr) * DD + sq * 8;
  const float* pBg = x2b + (size_t)gj * DD + sq * 8;
  __bf16* dA = sA + sr * SAK + sq * 8;
  __bf16* dB = sB + sr * SAK + sq * 8;

  const __bf16* fAp = sA + (wi * 32 + ln) * SAK + kh * 8;
  const __bf16* fBp = sB + (wj * 32 + ln) * SAK + kh * 8;

  floatx16 acc = {};

  for (int kc = 0; kc < DD; kc += 32) {
    const float4 a0 = *(const float4*)(pAg + kc);
    const float4 a1 = *(const float4*)(pAg + kc + 4);
    const float4 b0 = *(const float4*)(pBg + kc);
    const float4 b1 = *(const float4*)(pBg + kc + 4);
    __syncthreads();
    {
      bf16x8 va, vb;
      va[0] = (__bf16)a0.x; va[1] = (__bf16)a0.y; va[2] = (__bf16)a0.z; va[3] = (__bf16)a0.w;
      va[4] = (__bf16)a1.x; va[5] = (__bf16)a1.y; va[6] = (__bf16)a1.z; va[7] = (__bf16)a1.w;
      vb[0] = (__bf16)b0.x; vb[1] = (__bf16)b0.y; vb[2] = (__bf16)b0.z; vb[3] = (__bf16)b0.w;
      vb[4] = (__bf16)b1.x; vb[5] = (__bf16)b1.y; vb[6] = (__bf16)b1.z; vb[7] = (__bf16)b1.w;
      *(bf16x8*)dA = va;
      *(bf16x8*)dB = vb;
    }
    __syncthreads();
    const bf16x8 fa0 = *(const bf16x8*)fAp;
    const bf16x8 fb0 = *(const bf16x8*)fBp;
    const bf16x8 fa1 = *(const bf16x8*)(fAp + 16);
    const bf16x8 fb1 = *(const bf16x8*)(fBp + 16);
    acc = __builtin_amdgcn_mfma_f32_32x32x16_bf16(fa0, fb0, acc, 0, 0, 0);
    acc = __builtin_amdgcn_mfma_f32_32x32x16_bf16(fa1, fb1, acc, 0, 0, 0);
  }

  // epilogue: C layout col=lane&31 (j), row=(reg&3)+8*(reg>>2)+4*(lane>>5) (i)
  const int j = j0 + wj * 32 + ln;
  const int jc = j < 0 ? 0 : (j > TT - 1 ? TT - 1 : j);
  const float r2 = rinv2[b * TT + jc];
  float* cb = costX + (size_t)b * (TT * JSTR);
#pragma unroll
  for (int reg = 0; reg < 16; ++reg) {
    const int i = i0 + wi * 32 + (reg & 3) + 8 * (reg >> 2) + 4 * kh;
    const int jo = j - i + 50;
    if ((unsigned)j < TT && (unsigned)jo <= 100) {
      cb[(size_t)i * JSTR + jo] = 1.0f - acc[reg] * rinv1[b * TT + i] * r2;
    }
  }
}

// ---------- Kernel R: reshape [b][i][jo] -> diagonal-major [b][d][lane] ----------
// Lane l of diagonal d holds band cell k = 2l+p (p = d&1), i = (d>>1)+l+p-25, j = d-i.
// Invalid cells (outside band or outside [0,512)^2) get BIG; DP needs no masking.
__global__ __launch_bounds__(256) void reshape_kernel(const float* __restrict__ costX,
                                                      float* __restrict__ diag) {
  const int wv = (blockIdx.x * 256 + threadIdx.x) >> 6;  // global wave id
  const int l = threadIdx.x & 63;
  const int b = wv >> 10;
  const int d = wv & 1023;  // 0..1023 (1023 is pad, written BIG)
  const int p = d & 1;
  const int i = (d >> 1) + l + p - 25;
  const int j = d - i;
  const int k = 2 * l + p;
  float v = BIGF;
  if (d <= 1022 && k <= 100 && i >= 0 && i < TT && j >= 0 && j < TT) {
    v = costX[((size_t)b * TT + i) * JSTR + (100 - k)];
  }
  diag[((size_t)b * DROWS + d) * 64 + l] = v;
}

// ---------- Kernel C: anti-diagonal DP, one wave per batch, coalesced diag reads ----------
__global__ __launch_bounds__(64) void dtw_dp_kernel(const float* __restrict__ diag,
                                                    float* __restrict__ out) {
  const int b = blockIdx.x;
  const int l = threadIdx.x;
  const float* base = diag + (size_t)b * (DROWS * 64);
  const float* pO = base + 64 + l;   // d = 1
  const float* pE = base + 128 + l;  // d = 2
  float cr[32];
#pragma unroll
  for (int t = 0; t < 16; ++t) {
    cr[2 * t] = *pO; pO += 128;
    cr[2 * t + 1] = *pE; pE += 128;
  }
  float prev2 = BIGF;
  const float c00 = base[25];          // cost(0,0) lives at d=0, lane 25
  float prev1 = (l == 25) ? c00 : BIGF;
  float ans = BIGF;
  for (int it = 0; it < 32; ++it) {
#pragma unroll
    for (int u = 0; u < 16; ++u) {
      // odd diagonal
      const float c1 = cr[2 * u];
      cr[2 * u] = *pO; pO += 128;  // prefetch d+32 (stays within DROWS pad)
      const float sh = dpp_wave_shl1(prev1, BIGF);
      const float m3 = fminf(fminf(prev1, sh), prev2);
      prev2 = prev1;
      prev1 = c1 + m3;
      // even diagonal
      const float c2 = cr[2 * u + 1];
      cr[2 * u + 1] = *pE; pE += 128;
      const float sh2 = dpp_wave_shr1(prev1, BIGF);
      const float m32 = fminf(fminf(sh2, prev1), prev2);
      prev2 = prev1;
      prev1 = c2 + m32;
      if (u == 14 && it == 31) ans = prev1;  // d = 1022 -> cell (511,511) at lane 25
    }
  }
  if (l == 25) out[b] = ans;
}

extern "C" void kernel_launch(void* const* d_in, const int* in_sizes, int n_in,
                              void* d_out, int out_size, void* d_ws, size_t ws_size,
                              hipStream_t stream) {
  const float* x1 = (const float*)d_in[0];
  const float* x2 = (const float*)d_in[1];
  float* out = (float*)d_out;
  float* costX = (float*)d_ws;                       // 64*512*104 floats = 13.6 MB
  float* diag = costX + (size_t)NB * TT * JSTR;      // 64*1088*64 floats = 17.8 MB
  float* rinv1 = diag + (size_t)NB * DROWS * 64;     // 64*512 floats
  float* rinv2 = rinv1 + NB * TT;                    // 64*512 floats

  norm_kernel<<<16384, 256, 0, stream>>>(x1, x2, rinv1, rinv2);
  dim3 g(3, 8, NB);
  cost_kernel<<<g, 256, 0, stream>>>(x1, x2, rinv1, rinv2, costX);
  reshape_kernel<<<NB * 1024 / 4, 256, 0, stream>>>(costX, diag);
  dtw_dp_kernel<<<NB, 64, 0, stream>>>(diag, out);
}

// Round 4
// 156.074 us; speedup vs baseline: 1.2567x; 1.1497x over previous
//
#include <hip/hip_runtime.h>

#define BIGF 1e9f
#define TT 512
#define DD 256
#define NB 64
#define DROWS 1088    // diag rows per batch (1023 used + prefetch overrun pad)
#define SAK 40        // LDS row stride in bf16 (32 data + 8 pad)

typedef float floatx16 __attribute__((ext_vector_type(16)));
typedef __bf16 bf16x8 __attribute__((ext_vector_type(8)));

// ---------- DPP wave shifts: lane i <- lane i-1 (shr) / lane i+1 (shl); invalid lanes get `oldv`
__device__ __forceinline__ float dpp_wave_shr1(float x, float oldv) {
  int r = __builtin_amdgcn_update_dpp(__builtin_bit_cast(int, oldv),
                                      __builtin_bit_cast(int, x),
                                      0x138, 0xF, 0xF, false);  // WAVE_SHR1
  return __builtin_bit_cast(float, r);
}
__device__ __forceinline__ float dpp_wave_shl1(float x, float oldv) {
  int r = __builtin_amdgcn_update_dpp(__builtin_bit_cast(int, oldv),
                                      __builtin_bit_cast(int, x),
                                      0x130, 0xF, 0xF, false);  // WAVE_SHL1
  return __builtin_bit_cast(float, r);
}

// ---------- Kernel F: fill diag buffer with BIG (poison 0xAA would read as -3e-13) ----------
__global__ __launch_bounds__(256) void fill_diag(float4* __restrict__ diag4) {
  const int idx = blockIdx.x * 256 + threadIdx.x;  // NB*DROWS*64/4 = 1114112 float4s
  diag4[idx] = make_float4(BIGF, BIGF, BIGF, BIGF);
}

// ---------- Kernel B: banded cost via bf16 MFMA + fused norms, written in diag layout ----------
// 64x64 (i,j) tile per block; 4 waves in 2x2; each wave one 32x32 MFMA accumulator.
// Norms are side-accumulated in fp32 from the staged data (each row's 256 floats are
// read by 4 staging threads across the k-loop), reduced via shfl_xor, published in LDS.
__global__ __launch_bounds__(256) void cost_kernel(const float* __restrict__ x1,
                                                   const float* __restrict__ x2,
                                                   float* __restrict__ diag) {
  const int jt = blockIdx.x;  // 0..2
  const int it = blockIdx.y;  // 0..7
  const int b = blockIdx.z;   // 0..63
  const int i0 = it * 64;
  const int j0 = i0 - 50 + jt * 64;

  __shared__ __align__(16) __bf16 sA[64 * SAK];
  __shared__ __align__(16) __bf16 sB[64 * SAK];
  __shared__ float rA[64];  // 1/max(||x1_i||, eps) per tile row
  __shared__ float rB[64];

  const int t = threadIdx.x;
  const int lane = t & 63;
  const int w = t >> 6;       // wave 0..3
  const int wi = w >> 1;      // i-subtile (0/1)
  const int wj = w & 1;       // j-subtile (0/1)
  const int ln = lane & 31;
  const int kh = lane >> 5;   // k-half (0/1)

  // staging mapping: thread t loads row (t>>2), 8 floats at quarter (t&3)
  const int sr = t >> 2;
  const int sq = t & 3;
  const float* x1b = x1 + (size_t)b * (TT * DD);
  const float* x2b = x2 + (size_t)b * (TT * DD);
  int gj = j0 + sr;
  gj = gj < 0 ? 0 : (gj > TT - 1 ? TT - 1 : gj);
  const float* pAg = x1b + (size_t)(i0 + sr) * DD + sq * 8;
  const float* pBg = x2b + (size_t)gj * DD + sq * 8;
  __bf16* dA = sA + sr * SAK + sq * 8;
  __bf16* dB = sB + sr * SAK + sq * 8;

  const __bf16* fAp = sA + (wi * 32 + ln) * SAK + kh * 8;
  const __bf16* fBp = sB + (wj * 32 + ln) * SAK + kh * 8;

  floatx16 acc = {};
  float pa = 0.f, pb = 0.f;  // sum-of-squares partials (fp32, from original data)

  for (int kc = 0; kc < DD; kc += 32) {
    const float4 a0 = *(const float4*)(pAg + kc);
    const float4 a1 = *(const float4*)(pAg + kc + 4);
    const float4 b0 = *(const float4*)(pBg + kc);
    const float4 b1 = *(const float4*)(pBg + kc + 4);
    pa += a0.x * a0.x + a0.y * a0.y + a0.z * a0.z + a0.w * a0.w;
    pa += a1.x * a1.x + a1.y * a1.y + a1.z * a1.z + a1.w * a1.w;
    pb += b0.x * b0.x + b0.y * b0.y + b0.z * b0.z + b0.w * b0.w;
    pb += b1.x * b1.x + b1.y * b1.y + b1.z * b1.z + b1.w * b1.w;
    __syncthreads();
    {
      bf16x8 va, vb;
      va[0] = (__bf16)a0.x; va[1] = (__bf16)a0.y; va[2] = (__bf16)a0.z; va[3] = (__bf16)a0.w;
      va[4] = (__bf16)a1.x; va[5] = (__bf16)a1.y; va[6] = (__bf16)a1.z; va[7] = (__bf16)a1.w;
      vb[0] = (__bf16)b0.x; vb[1] = (__bf16)b0.y; vb[2] = (__bf16)b0.z; vb[3] = (__bf16)b0.w;
      vb[4] = (__bf16)b1.x; vb[5] = (__bf16)b1.y; vb[6] = (__bf16)b1.z; vb[7] = (__bf16)b1.w;
      *(bf16x8*)dA = va;
      *(bf16x8*)dB = vb;
    }
    __syncthreads();
    const bf16x8 fa0 = *(const bf16x8*)fAp;
    const bf16x8 fb0 = *(const bf16x8*)fBp;
    const bf16x8 fa1 = *(const bf16x8*)(fAp + 16);
    const bf16x8 fb1 = *(const bf16x8*)(fBp + 16);
    acc = __builtin_amdgcn_mfma_f32_32x32x16_bf16(fa0, fb0, acc, 0, 0, 0);
    acc = __builtin_amdgcn_mfma_f32_32x32x16_bf16(fa1, fb1, acc, 0, 0, 0);
  }

  // reduce sumsq across the 4 staging threads of each row (lanes t^1, t^2 share sr)
  pa += __shfl_xor(pa, 1, 64); pa += __shfl_xor(pa, 2, 64);
  pb += __shfl_xor(pb, 1, 64); pb += __shfl_xor(pb, 2, 64);
  if (sq == 0) {
    rA[sr] = 1.0f / fmaxf(sqrtf(pa), 1e-8f);
    rB[sr] = 1.0f / fmaxf(sqrtf(pb), 1e-8f);
  }
  __syncthreads();

  // epilogue: C layout col=lane&31 (j), row=(reg&3)+8*(reg>>2)+4*(lane>>5) (i)
  // write directly to diag[b][d=i+j][l=(i-j+50)>>1]
  const int j = j0 + wj * 32 + ln;
  const float r2 = rB[wj * 32 + ln];
  float* db = diag + (size_t)b * (DROWS * 64);
#pragma unroll
  for (int reg = 0; reg < 16; ++reg) {
    const int ri = wi * 32 + (reg & 3) + 8 * (reg >> 2) + 4 * kh;
    const int i = i0 + ri;
    const int k = i - j + 50;
    if ((unsigned)j < TT && (unsigned)k <= 100) {
      const float v = 1.0f - acc[reg] * rA[ri] * r2;
      db[(size_t)(i + j) * 64 + (k >> 1)] = v;
    }
  }
}

// ---------- Kernel C: anti-diagonal DP, one wave per batch, coalesced diag reads ----------
// Band offset k = i-j+50; lane l holds cell k = 2l+p (p = d&1).
// new[k] = c + min(prev1[k-1], prev1[k+1], prev2[k])
//   p=1 (odd d): k-1 -> same lane, k+1 -> wave_shl1;  p=0: k-1 -> wave_shr1, k+1 -> same lane.
// Each step loads 64 contiguous floats (256 B); 32-deep register ring prefetch.
__global__ __launch_bounds__(64) void dtw_dp_kernel(const float* __restrict__ diag,
                                                    float* __restrict__ out) {
  const int b = blockIdx.x;
  const int l = threadIdx.x;
  const float* base = diag + (size_t)b * (DROWS * 64);
  const float* pO = base + 64 + l;   // d = 1
  const float* pE = base + 128 + l;  // d = 2
  float cr[32];
#pragma unroll
  for (int t = 0; t < 16; ++t) {
    cr[2 * t] = *pO; pO += 128;
    cr[2 * t + 1] = *pE; pE += 128;
  }
  float prev2 = BIGF;
  const float c00 = base[25];          // cost(0,0) lives at d=0, lane 25
  float prev1 = (l == 25) ? c00 : BIGF;
  float ans = BIGF;
  for (int it = 0; it < 32; ++it) {
#pragma unroll
    for (int u = 0; u < 16; ++u) {
      // odd diagonal
      const float c1 = cr[2 * u];
      cr[2 * u] = *pO; pO += 128;  // prefetch d+32 (stays within DROWS pad)
      const float sh = dpp_wave_shl1(prev1, BIGF);
      const float m3 = fminf(fminf(prev1, sh), prev2);
      prev2 = prev1;
      prev1 = c1 + m3;
      // even diagonal
      const float c2 = cr[2 * u + 1];
      cr[2 * u + 1] = *pE; pE += 128;
      const float sh2 = dpp_wave_shr1(prev1, BIGF);
      const float m32 = fminf(fminf(sh2, prev1), prev2);
      prev2 = prev1;
      prev1 = c2 + m32;
      if (u == 14 && it == 31) ans = prev1;  // d = 1022 -> cell (511,511) at lane 25
    }
  }
  if (l == 25) out[b] = ans;
}

extern "C" void kernel_launch(void* const* d_in, const int* in_sizes, int n_in,
                              void* d_out, int out_size, void* d_ws, size_t ws_size,
                              hipStream_t stream) {
  const float* x1 = (const float*)d_in[0];
  const float* x2 = (const float*)d_in[1];
  float* out = (float*)d_out;
  float* diag = (float*)d_ws;  // 64*1088*64 floats = 17.8 MB

  fill_diag<<<NB * DROWS * 64 / 4 / 256, 256, 0, stream>>>((float4*)diag);
  dim3 g(3, 8, NB);
  cost_kernel<<<g, 256, 0, stream>>>(x1, x2, diag);
  dtw_dp_kernel<<<NB, 64, 0, stream>>>(diag, out);
}

// Round 5
// 130.857 us; speedup vs baseline: 1.4989x; 1.1927x over previous
//
#include <hip/hip_runtime.h>

#define BIGF 1e9f
#define TT 512
#define DD 256
#define NB 64
#define DROWS 1088    // diag rows per batch (1023 used + prefetch overrun pad)
#define SAK 40        // LDS row stride in bf16 (32 data + 8 pad)
#define FROWS 180     // filled boundary rows per batch: d in [0,64) and [972,1088)

typedef float floatx16 __attribute__((ext_vector_type(16)));
typedef __bf16 bf16x8 __attribute__((ext_vector_type(8)));

// ---------- DPP wave shifts: lane i <- lane i-1 (shr) / lane i+1 (shl); invalid lanes get `oldv`
__device__ __forceinline__ float dpp_wave_shr1(float x, float oldv) {
  int r = __builtin_amdgcn_update_dpp(__builtin_bit_cast(int, oldv),
                                      __builtin_bit_cast(int, x),
                                      0x138, 0xF, 0xF, false);  // WAVE_SHR1
  return __builtin_bit_cast(float, r);
}
__device__ __forceinline__ float dpp_wave_shl1(float x, float oldv) {
  int r = __builtin_amdgcn_update_dpp(__builtin_bit_cast(int, oldv),
                                      __builtin_bit_cast(int, x),
                                      0x130, 0xF, 0xF, false);  // WAVE_SHL1
  return __builtin_bit_cast(float, r);
}

// ---------- Kernel F: BIG-fill ONLY the corner diagonals (d<64, d>=972) ----------
// Middle diagonals: all lanes l<=50 cells are valid (written by cost_kernel);
// l>=51 and l==50-odd are masked arithmetically in the DP. Poison elsewhere is never read unmasked.
__global__ __launch_bounds__(256) void fill_diag(float4* __restrict__ diag4) {
  const int idx = blockIdx.x * 256 + threadIdx.x;  // NB*FROWS*16 = 184320
  const int b = idx / (FROWS * 16);
  const int rem = idx - b * (FROWS * 16);
  const int r = rem >> 4;
  const int f = rem & 15;
  const int d = (r < 64) ? r : (r + 908);  // [0,64) U [972,1088)
  diag4[((size_t)b * DROWS + d) * 16 + f] = make_float4(BIGF, BIGF, BIGF, BIGF);
}

// ---------- Kernel B: banded cost via bf16 MFMA + fused norms, written in diag layout ----------
// 64x64 (i,j) tile per block; 4 waves in 2x2; each wave one 32x32 MFMA accumulator.
// Grid is 1D, decoded so all 24 tiles of batch b share XCD b%8 (block n -> XCD n%8 heuristic):
// x1/x2 of a batch stay L2-resident -> fetch ~= compulsory 67 MB.
__global__ __launch_bounds__(256) void cost_kernel(const float* __restrict__ x1,
                                                   const float* __restrict__ x2,
                                                   float* __restrict__ diag) {
  const int n = blockIdx.x;
  const int b = n & 63;       // batch; b%8 == n%8 -> XCD
  const int m = n >> 6;       // 0..23
  const int it = m & 7;       // i-tile
  const int jt = m >> 3;      // j-tile 0..2
  const int i0 = it * 64;
  const int j0 = i0 - 50 + jt * 64;

  __shared__ __align__(16) __bf16 sA[64 * SAK];
  __shared__ __align__(16) __bf16 sB[64 * SAK];
  __shared__ float rA[64];  // 1/max(||x1_i||, eps) per tile row
  __shared__ float rB[64];

  const int t = threadIdx.x;
  const int lane = t & 63;
  const int w = t >> 6;       // wave 0..3
  const int wi = w >> 1;      // i-subtile (0/1)
  const int wj = w & 1;       // j-subtile (0/1)
  const int ln = lane & 31;
  const int kh = lane >> 5;   // k-half (0/1)

  // staging mapping: thread t loads row (t>>2), 8 floats at quarter (t&3)
  const int sr = t >> 2;
  const int sq = t & 3;
  const float* x1b = x1 + (size_t)b * (TT * DD);
  const float* x2b = x2 + (size_t)b * (TT * DD);
  int gj = j0 + sr;
  gj = gj < 0 ? 0 : (gj > TT - 1 ? TT - 1 : gj);
  const float* pAg = x1b + (size_t)(i0 + sr) * DD + sq * 8;
  const float* pBg = x2b + (size_t)gj * DD + sq * 8;
  __bf16* dA = sA + sr * SAK + sq * 8;
  __bf16* dB = sB + sr * SAK + sq * 8;

  const __bf16* fAp = sA + (wi * 32 + ln) * SAK + kh * 8;
  const __bf16* fBp = sB + (wj * 32 + ln) * SAK + kh * 8;

  floatx16 acc = {};
  float pa = 0.f, pb = 0.f;  // sum-of-squares partials (fp32, from original data)

  for (int kc = 0; kc < DD; kc += 32) {
    const float4 a0 = *(const float4*)(pAg + kc);
    const float4 a1 = *(const float4*)(pAg + kc + 4);
    const float4 b0 = *(const float4*)(pBg + kc);
    const float4 b1 = *(const float4*)(pBg + kc + 4);
    pa += a0.x * a0.x + a0.y * a0.y + a0.z * a0.z + a0.w * a0.w;
    pa += a1.x * a1.x + a1.y * a1.y + a1.z * a1.z + a1.w * a1.w;
    pb += b0.x * b0.x + b0.y * b0.y + b0.z * b0.z + b0.w * b0.w;
    pb += b1.x * b1.x + b1.y * b1.y + b1.z * b1.z + b1.w * b1.w;
    __syncthreads();
    {
      bf16x8 va, vb;
      va[0] = (__bf16)a0.x; va[1] = (__bf16)a0.y; va[2] = (__bf16)a0.z; va[3] = (__bf16)a0.w;
      va[4] = (__bf16)a1.x; va[5] = (__bf16)a1.y; va[6] = (__bf16)a1.z; va[7] = (__bf16)a1.w;
      vb[0] = (__bf16)b0.x; vb[1] = (__bf16)b0.y; vb[2] = (__bf16)b0.z; vb[3] = (__bf16)b0.w;
      vb[4] = (__bf16)b1.x; vb[5] = (__bf16)b1.y; vb[6] = (__bf16)b1.z; vb[7] = (__bf16)b1.w;
      *(bf16x8*)dA = va;
      *(bf16x8*)dB = vb;
    }
    __syncthreads();
    const bf16x8 fa0 = *(const bf16x8*)fAp;
    const bf16x8 fb0 = *(const bf16x8*)fBp;
    const bf16x8 fa1 = *(const bf16x8*)(fAp + 16);
    const bf16x8 fb1 = *(const bf16x8*)(fBp + 16);
    acc = __builtin_amdgcn_mfma_f32_32x32x16_bf16(fa0, fb0, acc, 0, 0, 0);
    acc = __builtin_amdgcn_mfma_f32_32x32x16_bf16(fa1, fb1, acc, 0, 0, 0);
  }

  // reduce sumsq across the 4 staging threads of each row (lanes t^1, t^2 share sr)
  pa += __shfl_xor(pa, 1, 64); pa += __shfl_xor(pa, 2, 64);
  pb += __shfl_xor(pb, 1, 64); pb += __shfl_xor(pb, 2, 64);
  if (sq == 0) {
    rA[sr] = 1.0f / fmaxf(sqrtf(pa), 1e-8f);
    rB[sr] = 1.0f / fmaxf(sqrtf(pb), 1e-8f);
  }
  __syncthreads();

  // epilogue: C layout col=lane&31 (j), row=(reg&3)+8*(reg>>2)+4*(lane>>5) (i)
  // write directly to diag[b][d=i+j][l=(i-j+50)>>1]
  const int j = j0 + wj * 32 + ln;
  const float r2 = rB[wj * 32 + ln];
  float* db = diag + (size_t)b * (DROWS * 64);
#pragma unroll
  for (int reg = 0; reg < 16; ++reg) {
    const int ri = wi * 32 + (reg & 3) + 8 * (reg >> 2) + 4 * kh;
    const int i = i0 + ri;
    const int k = i - j + 50;
    if ((unsigned)j < TT && (unsigned)k <= 100) {
      const float v = 1.0f - acc[reg] * rA[ri] * r2;
      db[(size_t)(i + j) * 64 + (k >> 1)] = v;
    }
  }
}

// ---------- Kernel C: anti-diagonal DP, one wave per batch, coalesced diag reads ----------
// Band offset k = i-j+50; lane l holds cell k = 2l+p (p = d&1).
// new[k] = c + min(prev1[k-1], prev1[k+1], prev2[k])
//   p=1 (odd d): k-1 -> same lane, k+1 -> wave_shl1;  p=0: k-1 -> wave_shr1, k+1 -> same lane.
// Lanes l>=51 (and l==50 on odd d) are permanently out of band: their cost is forced
// to BIG via a loop-invariant cndmask on the prefetched value (off the critical chain),
// so only corner diagonals need memory pre-fill.
__global__ __launch_bounds__(64) void dtw_dp_kernel(const float* __restrict__ diag,
                                                    float* __restrict__ out) {
  const int b = blockIdx.x;
  const int l = threadIdx.x;
  const bool inv_odd = (l >= 50);   // k=2l+1 > 100
  const bool inv_even = (l >= 51);  // k=2l   > 100
  const float* base = diag + (size_t)b * (DROWS * 64);
  const float* pO = base + 64 + l;   // d = 1
  const float* pE = base + 128 + l;  // d = 2
  float cr[32];
#pragma unroll
  for (int t = 0; t < 16; ++t) {
    cr[2 * t] = *pO; pO += 128;
    cr[2 * t + 1] = *pE; pE += 128;
  }
  float prev2 = BIGF;
  const float c00 = base[25];          // cost(0,0) lives at d=0, lane 25
  float prev1 = (l == 25) ? c00 : BIGF;
  float ans = BIGF;
  for (int it = 0; it < 32; ++it) {
#pragma unroll
    for (int u = 0; u < 16; ++u) {
      // odd diagonal
      const float c1 = inv_odd ? BIGF : cr[2 * u];
      cr[2 * u] = *pO; pO += 128;  // prefetch d+32 (stays within DROWS pad)
      const float sh = dpp_wave_shl1(prev1, BIGF);
      const float m3 = fminf(fminf(prev1, sh), prev2);
      prev2 = prev1;
      prev1 = c1 + m3;
      // even diagonal
      const float c2 = inv_even ? BIGF : cr[2 * u + 1];
      cr[2 * u + 1] = *pE; pE += 128;
      const float sh2 = dpp_wave_shr1(prev1, BIGF);
      const float m32 = fminf(fminf(sh2, prev1), prev2);
      prev2 = prev1;
      prev1 = c2 + m32;
      if (u == 14 && it == 31) ans = prev1;  // d = 1022 -> cell (511,511) at lane 25
    }
  }
  if (l == 25) out[b] = ans;
}

extern "C" void kernel_launch(void* const* d_in, const int* in_sizes, int n_in,
                              void* d_out, int out_size, void* d_ws, size_t ws_size,
                              hipStream_t stream) {
  const float* x1 = (const float*)d_in[0];
  const float* x2 = (const float*)d_in[1];
  float* out = (float*)d_out;
  float* diag = (float*)d_ws;  // 64*1088*64 floats = 17.8 MB

  fill_diag<<<NB * FROWS * 16 / 256, 256, 0, stream>>>((float4*)diag);
  cost_kernel<<<NB * 24, 256, 0, stream>>>(x1, x2, diag);
  dtw_dp_kernel<<<NB, 64, 0, stream>>>(diag, out);
}